// Round 5
// baseline (117.468 us; speedup 1.0000x reference)
//
#include <hip/hip_runtime.h>
#include <stdint.h>

#define B_ 64
#define K_ 8192
#define O_ 8192
#define R_ 64
#define KS 8   // K-split ways (one per 8-wave block column)

typedef __attribute__((ext_vector_type(8))) short s16x8;      // 8 bf16
typedef __attribute__((ext_vector_type(4))) float f32x4;
typedef __attribute__((ext_vector_type(4))) int iv4;
typedef __attribute__((ext_vector_type(4))) uint32_t uv4;

// round-to-nearest-even f32 -> bf16, packed pair
__device__ __forceinline__ uint32_t rne_pack(float a, float b) {
  uint32_t ua = __float_as_uint(a), ub = __float_as_uint(b);
  ua += 0x7fffu + ((ua >> 16) & 1u);
  ub += 0x7fffu + ((ub >> 16) & 1u);
  return (ua >> 16) | (ub & 0xffff0000u);
}

// (w - 128) in [-128,127]: EXACT in bf16, truncation suffices
__device__ __forceinline__ uint32_t wpack(int w0, int w1) {
  float f0 = (float)(w0 - 128);
  float f1 = (float)(w1 - 128);
  return (__float_as_uint(f0) >> 16) | (__float_as_uint(f1) & 0xffff0000u);
}

__device__ __forceinline__ s16x8 bfrag_from(iv4 a, iv4 b) {
  union { uint32_t u[4]; s16x8 v; } r;
  r.u[0] = wpack(a[0], a[1]); r.u[1] = wpack(a[2], a[3]);
  r.u[2] = wpack(b[0], b[1]); r.u[3] = wpack(b[2], b[3]);
  return r.v;
}

__device__ __forceinline__ s16x8 afrag(uv4 x) {
  union { uv4 u; s16x8 v; } r; r.u = x; return r.v;
}

// ---------------------------------------------------------------------------
// k_prep: (a) all 256 blocks: pack x (fp32 [64][8192]) into MFMA-fragment-
//         major bf16: element addr ((C*4+m)*64 + lane)*8 + j holds
//         x[m*16 + (lane&15)][C*32 + (lane>>4)*8 + j].  One dwordx4 per frag.
//         (b) blocks 0..63: partial mid = x @ lora_A^T over a 128-wide K
//         slab, accumulated via fp32 atomicAdd (mid zeroed by memset).
// ---------------------------------------------------------------------------
__global__ __launch_bounds__(256) void k_prep(
    const float* __restrict__ x, const float* __restrict__ lora_A,
    uint16_t* __restrict__ xf, float* __restrict__ mid) {
  const int t = threadIdx.x;
  const int blk = blockIdx.x;

  {  // one fragment per thread: 65536 frags = 256 blocks x 256 threads
    const int gtid = blk * 256 + t;
    const int l = gtid & 63;
    const int m = (gtid >> 6) & 3;
    const int C = gtid >> 8;
    const int row = m * 16 + (l & 15);
    const int col = C * 32 + (l >> 4) * 8;
    const float* xp = x + (size_t)row * K_ + col;
    float4 v0 = *(const float4*)xp;
    float4 v1 = *(const float4*)(xp + 4);
    uint4 p;
    p.x = rne_pack(v0.x, v0.y);
    p.y = rne_pack(v0.z, v0.w);
    p.z = rne_pack(v1.x, v1.y);
    p.w = rne_pack(v1.z, v1.w);
    *(uint4*)(xf + (size_t)gtid * 8) = p;   // coalesced
  }

  if (blk >= 64) return;

  __shared__ float xs[64][133];
  __shared__ float as_[64][133];
  const int kr0 = blk * 128;
  const int row = t >> 2, seg = t & 3;
#pragma unroll
  for (int j = 0; j < 8; ++j) {
    const int c = seg * 32 + j * 4;
    float4 vx = *(const float4*)(x + (size_t)row * K_ + kr0 + c);
    float4 va = *(const float4*)(lora_A + (size_t)row * K_ + kr0 + c);
    xs[row][c] = vx.x; xs[row][c + 1] = vx.y; xs[row][c + 2] = vx.z; xs[row][c + 3] = vx.w;
    as_[row][c] = va.x; as_[row][c + 1] = va.y; as_[row][c + 2] = va.z; as_[row][c + 3] = va.w;
  }
  __syncthreads();

  const int bg = t >> 4, rg = t & 15;
  const int b0 = bg * 4, r0 = rg * 4;
  float acc[4][4];
#pragma unroll
  for (int i = 0; i < 4; ++i)
#pragma unroll
    for (int j = 0; j < 4; ++j) acc[i][j] = 0.f;

  for (int k = 0; k < 128; ++k) {
    float xv[4], av[4];
#pragma unroll
    for (int i = 0; i < 4; ++i) xv[i] = xs[b0 + i][k];
#pragma unroll
    for (int j = 0; j < 4; ++j) av[j] = as_[r0 + j][k];
#pragma unroll
    for (int i = 0; i < 4; ++i)
#pragma unroll
      for (int j = 0; j < 4; ++j) acc[i][j] += xv[i] * av[j];
  }

#pragma unroll
  for (int i = 0; i < 4; ++i)
#pragma unroll
    for (int j = 0; j < 4; ++j)
      atomicAdd(&mid[(b0 + i) * R_ + (r0 + j)], acc[i][j]);
}

// ---------------------------------------------------------------------------
// k_main: 4096 blocks x 512 threads. Block = (oc, ks): 16 out-cols x 64 batch
// x K=1024. Each of the 8 waves owns a K=128 slice: straight-line program,
// 8 nontemporal W loads -> 4 MFMA phases (x frags one dwordx4 each from
// L2-resident xf). No hot-path LDS/barriers. One LDS tree-reduce per block
// -> partial[ks][64][8192].
// ---------------------------------------------------------------------------
__global__ __launch_bounds__(512, 4) void k_main(
    const int* __restrict__ Wq, const uint16_t* __restrict__ xf,
    float* __restrict__ part) {
  __shared__ float red[8][64][17];   // ~34 KB

  const int t = threadIdx.x;
  const int w = t >> 6, lane = t & 63, il = lane & 15, g = lane >> 4;
  const int oc = blockIdx.x >> 3;    // 0..511
  const int ks = blockIdx.x & 7;     // 0..7
  const int o0 = oc * 16;
  const int k0 = ks * 1024 + w * 128;
  const int c0 = ks * 32 + w * 4;    // global 32-chunk index of this wave

  const int* wsrc = Wq + (size_t)(o0 + il) * K_ + k0 + g * 8;
  const uint16_t* xs = xf + ((size_t)c0 * 4 * 64 + lane) * 8;

  iv4 rwa0, rwb0, rwa1, rwb1, rwa2, rwb2, rwa3, rwb3;
  uv4 xa0, xa1, xa2, xa3, xb0, xb1, xb2, xb3;
  f32x4 acc0 = {0.f,0.f,0.f,0.f}, acc1 = {0.f,0.f,0.f,0.f};
  f32x4 acc2 = {0.f,0.f,0.f,0.f}, acc3 = {0.f,0.f,0.f,0.f};

#define WLOAD(C_)                                                       \
  rwa##C_ = __builtin_nontemporal_load((const iv4*)(wsrc + (C_)*32));   \
  rwb##C_ = __builtin_nontemporal_load((const iv4*)(wsrc + (C_)*32 + 4));

#define XLOAD(BK, CC)                                   \
  x##BK##0 = *(const uv4*)(xs + ((CC)*4 + 0) * 512);    \
  x##BK##1 = *(const uv4*)(xs + ((CC)*4 + 1) * 512);    \
  x##BK##2 = *(const uv4*)(xs + ((CC)*4 + 2) * 512);    \
  x##BK##3 = *(const uv4*)(xs + ((CC)*4 + 3) * 512);

#define PH(BK, C_)                                                             \
  {                                                                            \
    s16x8 bf = bfrag_from(rwa##C_, rwb##C_);                                   \
    acc0 = __builtin_amdgcn_mfma_f32_16x16x32_bf16(afrag(x##BK##0), bf, acc0, 0, 0, 0); \
    acc1 = __builtin_amdgcn_mfma_f32_16x16x32_bf16(afrag(x##BK##1), bf, acc1, 0, 0, 0); \
    acc2 = __builtin_amdgcn_mfma_f32_16x16x32_bf16(afrag(x##BK##2), bf, acc2, 0, 0, 0); \
    acc3 = __builtin_amdgcn_mfma_f32_16x16x32_bf16(afrag(x##BK##3), bf, acc3, 0, 0, 0); \
  }

  // issue the whole W slice (HBM) first, then x (L2)
  WLOAD(0) WLOAD(1) WLOAD(2) WLOAD(3)
  XLOAD(a, 0) XLOAD(b, 1)
  PH(a, 0) XLOAD(a, 2)
  PH(b, 1) XLOAD(b, 3)
  PH(a, 2)
  PH(b, 3)

#undef WLOAD
#undef XLOAD
#undef PH

  // ---- block reduction over the 8 K-slices ----
#define RW(M, J) red[w][(M)*16 + g * 4 + (J)][il] = acc##M[J];
  RW(0,0) RW(0,1) RW(0,2) RW(0,3)
  RW(1,0) RW(1,1) RW(1,2) RW(1,3)
  RW(2,0) RW(2,1) RW(2,2) RW(2,3)
  RW(3,0) RW(3,1) RW(3,2) RW(3,3)
#undef RW
  __syncthreads();

  const int b = t >> 3;            // 0..63
  const int o2 = (t & 7) * 2;      // 0..14
  float s0 = 0.f, s1 = 0.f;
#pragma unroll
  for (int ww = 0; ww < 8; ++ww) {
    s0 += red[ww][b][o2];
    s1 += red[ww][b][o2 + 1];
  }
  float* pp = part + (size_t)ks * (B_ * O_) + (size_t)b * O_ + o0 + o2;
  pp[0] = s0;
  pp[1] = s1;
}

// ---------------------------------------------------------------------------
// k_fin: out = scale * (sum of 8 partials) + bias + 0.25 * (mid @ lora_B^T).
// ---------------------------------------------------------------------------
__global__ __launch_bounds__(256) void k_fin(
    const float* __restrict__ part, const float* __restrict__ scale,
    const float* __restrict__ lora_B, const float* __restrict__ bias,
    const float* __restrict__ mid, float* __restrict__ out) {
  __shared__ uint16_t midb[64][72];
  __shared__ uint16_t lob[16][72];

  const int t = threadIdx.x;
  const int o0 = blockIdx.x * 16;
  const int wave = t >> 6;
  const int lane = t & 63;
  const int il = lane & 15;
  const int g = lane >> 4;
  const int m0 = wave * 16;

  {  // stage mid (all threads) + lora_B tile (threads 0..63) as bf16
    const int row = t >> 2;
    const int r0 = (t & 3) * 16;
    const float* mp = mid + row * R_ + r0;
    float4 a0 = *(const float4*)(mp);
    float4 a1 = *(const float4*)(mp + 4);
    float4 a2 = *(const float4*)(mp + 8);
    float4 a3 = *(const float4*)(mp + 12);
    uint4 p0, p1;
    p0.x = rne_pack(a0.x, a0.y); p0.y = rne_pack(a0.z, a0.w);
    p0.z = rne_pack(a1.x, a1.y); p0.w = rne_pack(a1.z, a1.w);
    p1.x = rne_pack(a2.x, a2.y); p1.y = rne_pack(a2.z, a2.w);
    p1.z = rne_pack(a3.x, a3.y); p1.w = rne_pack(a3.z, a3.w);
    *(uint4*)&midb[row][r0] = p0;
    *(uint4*)&midb[row][r0 + 8] = p1;
    if (t < 64) {
      const int row2 = t >> 2;
      const float* lp = lora_B + (size_t)(o0 + row2) * R_ + r0;
      float4 c0 = *(const float4*)(lp);
      float4 c1 = *(const float4*)(lp + 4);
      float4 c2 = *(const float4*)(lp + 8);
      float4 c3 = *(const float4*)(lp + 12);
      uint4 q0, q1;
      q0.x = rne_pack(c0.x, c0.y); q0.y = rne_pack(c0.z, c0.w);
      q0.z = rne_pack(c1.x, c1.y); q0.w = rne_pack(c1.z, c1.w);
      q1.x = rne_pack(c2.x, c2.y); q1.y = rne_pack(c2.z, c2.w);
      q1.z = rne_pack(c3.x, c3.y); q1.w = rne_pack(c3.z, c3.w);
      *(uint4*)&lob[row2][r0] = q0;
      *(uint4*)&lob[row2][r0 + 8] = q1;
    }
  }
  __syncthreads();

  f32x4 acc2 = {0.f, 0.f, 0.f, 0.f};
#pragma unroll
  for (int kf = 0; kf < 2; ++kf) {
    s16x8 am = *(const s16x8*)&midb[m0 + il][kf * 32 + g * 8];
    s16x8 bl = *(const s16x8*)&lob[il][kf * 32 + g * 8];
    acc2 = __builtin_amdgcn_mfma_f32_16x16x32_bf16(am, bl, acc2, 0, 0, 0);
  }

  const float sc = scale[o0 + il];
  const float bi = bias[o0 + il];

#pragma unroll
  for (int j = 0; j < 4; ++j) {
    const int b = m0 + g * 4 + j;
    const size_t idx = (size_t)b * O_ + o0 + il;
    float s = 0.f;
#pragma unroll
    for (int k = 0; k < KS; ++k) s += part[(size_t)k * (B_ * O_) + idx];
    out[idx] = sc * s + bi + 0.25f * acc2[j];
  }
}

// ---------------------------------------------------------------------------
extern "C" void kernel_launch(void* const* d_in, const int* in_sizes, int n_in,
                              void* d_out, int out_size, void* d_ws, size_t ws_size,
                              hipStream_t stream) {
  const float* x = (const float*)d_in[0];
  const int* Wq = (const int*)d_in[1];
  const float* scale = (const float*)d_in[2];
  const float* lora_A = (const float*)d_in[3];
  const float* lora_B = (const float*)d_in[4];
  const float* bias = (const float*)d_in[5];
  float* out = (float*)d_out;

  uint16_t* xf = (uint16_t*)d_ws;                     // 1 MiB frag-major x
  float* mid = (float*)((char*)d_ws + (2u << 20));    // 16 KiB fp32
  float* part = (float*)((char*)d_ws + (4u << 20));   // 16 MiB fp32

  hipMemsetAsync(mid, 0, B_ * R_ * sizeof(float), stream);
  k_prep<<<256, 256, 0, stream>>>(x, lora_A, xf, mid);
  k_main<<<(O_ / 16) * KS, 512, 0, stream>>>(Wq, xf, part);
  k_fin<<<O_ / 16, 256, 0, stream>>>(part, scale, lora_B, bias, mid, out);
}

// Round 6
// 103.452 us; speedup vs baseline: 1.1355x; 1.1355x over previous
//
#include <hip/hip_runtime.h>
#include <stdint.h>

#define B_ 64
#define K_ 8192
#define O_ 8192
#define R_ 64
#define KSP 16          // K-split ways
#define KSL (K_ / KSP)  // 512 per block
#define NKF (KSL / 32)  // 16 k-frags per wave

typedef __attribute__((ext_vector_type(8))) short s16x8;      // 8 bf16
typedef __attribute__((ext_vector_type(4))) float f32x4;
typedef __attribute__((ext_vector_type(4))) int iv4;

// round-to-nearest-even f32 -> bf16, packed pair
__device__ __forceinline__ uint32_t rne_pack(float a, float b) {
  uint32_t ua = __float_as_uint(a), ub = __float_as_uint(b);
  ua += 0x7fffu + ((ua >> 16) & 1u);
  ub += 0x7fffu + ((ub >> 16) & 1u);
  return (ua >> 16) | (ub & 0xffff0000u);
}

// (w - 128) in [-128,127]: EXACT in bf16, truncation suffices
__device__ __forceinline__ uint32_t wpack(int w0, int w1) {
  float f0 = (float)(w0 - 128);
  float f1 = (float)(w1 - 128);
  return (__float_as_uint(f0) >> 16) | (__float_as_uint(f1) & 0xffff0000u);
}

__device__ __forceinline__ s16x8 bfrag_from(iv4 a, iv4 b) {
  union { uint32_t u[4]; s16x8 v; } r;
  r.u[0] = wpack(a[0], a[1]); r.u[1] = wpack(a[2], a[3]);
  r.u[2] = wpack(b[0], b[1]); r.u[3] = wpack(b[2], b[3]);
  return r.v;
}

// ---------------------------------------------------------------------------
// k_prep: (a) x (fp32 [64][8192]) -> bf16 xbg row-major (all 256 blocks)
//         (b) blocks 0..63: partial mid = x @ lora_A^T over a 128-wide K slab,
//             accumulated via fp32 atomicAdd (mid zeroed by memset).
// ---------------------------------------------------------------------------
__global__ __launch_bounds__(256) void k_prep(
    const float* __restrict__ x, const float* __restrict__ lora_A,
    uint16_t* __restrict__ xbg, float* __restrict__ mid) {
  const int t = threadIdx.x;
  const int blk = blockIdx.x;

  {  // x -> bf16, 2048 elems per block, 8 per thread
    const size_t base = (size_t)blk * 2048 + (size_t)t * 8;
    float4 v0 = *(const float4*)(x + base);
    float4 v1 = *(const float4*)(x + base + 4);
    uint4 p;
    p.x = rne_pack(v0.x, v0.y);
    p.y = rne_pack(v0.z, v0.w);
    p.z = rne_pack(v1.x, v1.y);
    p.w = rne_pack(v1.z, v1.w);
    *(uint4*)(xbg + base) = p;
  }

  if (blk >= 64) return;

  __shared__ float xs[64][133];
  __shared__ float as_[64][133];
  const int kr0 = blk * 128;
  const int row = t >> 2, seg = t & 3;
#pragma unroll
  for (int j = 0; j < 8; ++j) {
    const int c = seg * 32 + j * 4;
    float4 vx = *(const float4*)(x + (size_t)row * K_ + kr0 + c);
    float4 va = *(const float4*)(lora_A + (size_t)row * K_ + kr0 + c);
    xs[row][c] = vx.x; xs[row][c + 1] = vx.y; xs[row][c + 2] = vx.z; xs[row][c + 3] = vx.w;
    as_[row][c] = va.x; as_[row][c + 1] = va.y; as_[row][c + 2] = va.z; as_[row][c + 3] = va.w;
  }
  __syncthreads();

  const int bg = t >> 4, rg = t & 15;
  const int b0 = bg * 4, r0 = rg * 4;
  float acc[4][4];
#pragma unroll
  for (int i = 0; i < 4; ++i)
#pragma unroll
    for (int j = 0; j < 4; ++j) acc[i][j] = 0.f;

  for (int k = 0; k < 128; ++k) {
    float xv[4], av[4];
#pragma unroll
    for (int i = 0; i < 4; ++i) xv[i] = xs[b0 + i][k];
#pragma unroll
    for (int j = 0; j < 4; ++j) av[j] = as_[r0 + j][k];
#pragma unroll
    for (int i = 0; i < 4; ++i)
#pragma unroll
      for (int j = 0; j < 4; ++j) acc[i][j] += xv[i] * av[j];
  }

#pragma unroll
  for (int i = 0; i < 4; ++i)
#pragma unroll
    for (int j = 0; j < 4; ++j)
      atomicAdd(&mid[(b0 + i) * R_ + (r0 + j)], acc[i][j]);
}

// ---------------------------------------------------------------------------
// k_main: 1024 blocks = (band 0..63) x (ks 0..15). Block: 128 out-cols x
// 64 batch x K=512. x K-slice staged ONCE into 64 KB XOR-swizzled LDS; then
// the global path is a pure W stream: per-wave 4-deep named register banks,
// nontemporal loads, no barriers in the K-loop. 8 waves x 16 cols each.
// Partials -> part[ks][64][8192].
// ---------------------------------------------------------------------------
__global__ __launch_bounds__(512, 4) void k_main(
    const int* __restrict__ Wq, const uint16_t* __restrict__ xbg,
    float* __restrict__ part) {
  __shared__ uint4 xsl4[64 * 1024 / 16];   // 64 KB, byte-addressed, swizzled
  char* xsl = (char*)xsl4;

  const int t = threadIdx.x;
  const int w = t >> 6, lane = t & 63, il = lane & 15, g = lane >> 4;
  const int band = blockIdx.x >> 4;   // 0..63
  const int ks = blockIdx.x & 15;     // 0..15
  const int o0 = band * 128 + w * 16;
  const int k0 = ks * KSL;

  const int* wsrc = Wq + (size_t)(o0 + il) * K_ + k0 + g * 8;

  iv4 wa0, wb0, wa1, wb1, wa2, wb2, wa3, wb3;

#define LOADW(P, S)                                                       \
  do {                                                                    \
    wa##P = __builtin_nontemporal_load((const iv4*)(wsrc + (S) * 32));    \
    wb##P = __builtin_nontemporal_load((const iv4*)(wsrc + (S) * 32 + 4));\
  } while (0)

  // start the HBM W stream immediately: 4 banks in flight
  LOADW(0, 0); LOADW(1, 1); LOADW(2, 2); LOADW(3, 3);

  // ---- stage x K-slice into swizzled LDS (reads L2-hot xbg) ----
  {
    const int r = t >> 3, l8 = t & 7;             // 64 rows x 8 lanes
    const uint16_t* src = xbg + (size_t)r * K_ + k0 + l8 * 8;
    const uint32_t rowb = r * 1024;               // byte base of LDS row
    const uint32_t xr = (r & 7) << 4;
#pragma unroll
    for (int p = 0; p < 8; ++p) {
      uint4 v = *(const uint4*)(src + p * 64);    // 16 B: cols l8*8 + p*64
      *(uint4*)(xsl + rowb + ((l8 * 16 + p * 128) ^ xr)) = v;
    }
  }
  __syncthreads();

  // per-lane A-fragment address pieces (swizzle: byte ^= (row&7)<<4)
  const uint32_t ax = (il & 7) << 4;
  const uint32_t gc = g * 16;
  const uint32_t ab0 = (0 * 16 + il) * 1024;
  const uint32_t ab1 = (1 * 16 + il) * 1024;
  const uint32_t ab2 = (2 * 16 + il) * 1024;
  const uint32_t ab3 = (3 * 16 + il) * 1024;

  f32x4 acc0 = {0.f,0.f,0.f,0.f}, acc1 = {0.f,0.f,0.f,0.f};
  f32x4 acc2 = {0.f,0.f,0.f,0.f}, acc3 = {0.f,0.f,0.f,0.f};

#define PH(P, KK)                                                              \
  do {                                                                         \
    s16x8 bf = bfrag_from(wa##P, wb##P);                                       \
    const uint32_t co = (((uint32_t)(KK) * 64 + gc) ^ ax);                     \
    s16x8 a0 = *(const s16x8*)(xsl + ab0 + co);                                \
    s16x8 a1 = *(const s16x8*)(xsl + ab1 + co);                                \
    s16x8 a2 = *(const s16x8*)(xsl + ab2 + co);                                \
    s16x8 a3 = *(const s16x8*)(xsl + ab3 + co);                                \
    acc0 = __builtin_amdgcn_mfma_f32_16x16x32_bf16(a0, bf, acc0, 0, 0, 0);     \
    acc1 = __builtin_amdgcn_mfma_f32_16x16x32_bf16(a1, bf, acc1, 0, 0, 0);     \
    acc2 = __builtin_amdgcn_mfma_f32_16x16x32_bf16(a2, bf, acc2, 0, 0, 0);     \
    acc3 = __builtin_amdgcn_mfma_f32_16x16x32_bf16(a3, bf, acc3, 0, 0, 0);     \
    if ((KK) + 4 < NKF) LOADW(P, (KK) + 4);                                    \
  } while (0)

  for (int s = 0; s < NKF; s += 4) {
    PH(0, s + 0);
    PH(1, s + 1);
    PH(2, s + 2);
    PH(3, s + 3);
  }
#undef LOADW
#undef PH

  // ---- partial store: C/D layout col=il, batch row = m*16 + g*4 + j ----
  float* pp = part + (size_t)ks * (B_ * O_) + o0 + il;
#pragma unroll
  for (int j = 0; j < 4; ++j) {
    const int r = g * 4 + j;
    pp[(size_t)(r) * O_]      = acc0[j];
    pp[(size_t)(16 + r) * O_] = acc1[j];
    pp[(size_t)(32 + r) * O_] = acc2[j];
    pp[(size_t)(48 + r) * O_] = acc3[j];
  }
}

// ---------------------------------------------------------------------------
// k_fin: out = scale * (sum of 16 partials) + bias + 0.25 * (mid @ lora_B^T).
// ---------------------------------------------------------------------------
__global__ __launch_bounds__(256) void k_fin(
    const float* __restrict__ part, const float* __restrict__ scale,
    const float* __restrict__ lora_B, const float* __restrict__ bias,
    const float* __restrict__ mid, float* __restrict__ out) {
  __shared__ uint16_t midb[64][72];
  __shared__ uint16_t lob[16][72];

  const int t = threadIdx.x;
  const int o0 = blockIdx.x * 16;
  const int wave = t >> 6;
  const int lane = t & 63;
  const int il = lane & 15;
  const int g = lane >> 4;
  const int m0 = wave * 16;

  {  // stage mid (all threads) + lora_B tile (threads 0..63) as bf16
    const int row = t >> 2;
    const int r0 = (t & 3) * 16;
    const float* mp = mid + row * R_ + r0;
    float4 a0 = *(const float4*)(mp);
    float4 a1 = *(const float4*)(mp + 4);
    float4 a2 = *(const float4*)(mp + 8);
    float4 a3 = *(const float4*)(mp + 12);
    uint4 p0, p1;
    p0.x = rne_pack(a0.x, a0.y); p0.y = rne_pack(a0.z, a0.w);
    p0.z = rne_pack(a1.x, a1.y); p0.w = rne_pack(a1.z, a1.w);
    p1.x = rne_pack(a2.x, a2.y); p1.y = rne_pack(a2.z, a2.w);
    p1.z = rne_pack(a3.x, a3.y); p1.w = rne_pack(a3.z, a3.w);
    *(uint4*)&midb[row][r0] = p0;
    *(uint4*)&midb[row][r0 + 8] = p1;
    if (t < 64) {
      const int row2 = t >> 2;
      const float* lp = lora_B + (size_t)(o0 + row2) * R_ + r0;
      float4 c0 = *(const float4*)(lp);
      float4 c1 = *(const float4*)(lp + 4);
      float4 c2 = *(const float4*)(lp + 8);
      float4 c3 = *(const float4*)(lp + 12);
      uint4 q0, q1;
      q0.x = rne_pack(c0.x, c0.y); q0.y = rne_pack(c0.z, c0.w);
      q0.z = rne_pack(c1.x, c1.y); q0.w = rne_pack(c1.z, c1.w);
      q1.x = rne_pack(c2.x, c2.y); q1.y = rne_pack(c2.z, c2.w);
      q1.z = rne_pack(c3.x, c3.y); q1.w = rne_pack(c3.z, c3.w);
      *(uint4*)&lob[row2][r0] = q0;
      *(uint4*)&lob[row2][r0 + 8] = q1;
    }
  }
  __syncthreads();

  f32x4 acc2 = {0.f, 0.f, 0.f, 0.f};
#pragma unroll
  for (int kf = 0; kf < 2; ++kf) {
    s16x8 am = *(const s16x8*)&midb[m0 + il][kf * 32 + g * 8];
    s16x8 bl = *(const s16x8*)&lob[il][kf * 32 + g * 8];
    acc2 = __builtin_amdgcn_mfma_f32_16x16x32_bf16(am, bl, acc2, 0, 0, 0);
  }

  const float sc = scale[o0 + il];
  const float bi = bias[o0 + il];

#pragma unroll
  for (int j = 0; j < 4; ++j) {
    const int b = m0 + g * 4 + j;
    const size_t idx = (size_t)b * O_ + o0 + il;
    float s = 0.f;
#pragma unroll
    for (int k = 0; k < KSP; ++k) s += part[(size_t)k * (B_ * O_) + idx];
    out[idx] = sc * s + bi + 0.25f * acc2[j];
  }
}

// ---------------------------------------------------------------------------
extern "C" void kernel_launch(void* const* d_in, const int* in_sizes, int n_in,
                              void* d_out, int out_size, void* d_ws, size_t ws_size,
                              hipStream_t stream) {
  const float* x = (const float*)d_in[0];
  const int* Wq = (const int*)d_in[1];
  const float* scale = (const float*)d_in[2];
  const float* lora_A = (const float*)d_in[3];
  const float* lora_B = (const float*)d_in[4];
  const float* bias = (const float*)d_in[5];
  float* out = (float*)d_out;

  uint16_t* xbg = (uint16_t*)d_ws;                    // 1 MiB bf16 x, row-major
  float* mid = (float*)((char*)d_ws + (2u << 20));    // 16 KiB fp32
  float* part = (float*)((char*)d_ws + (4u << 20));   // 32 MiB fp32 (16 x 2 MiB)

  hipMemsetAsync(mid, 0, B_ * R_ * sizeof(float), stream);
  k_prep<<<256, 256, 0, stream>>>(x, lora_A, xbg, mid);
  k_main<<<KSP * (O_ / 128), 512, 0, stream>>>(Wq, xbg, part);
  k_fin<<<O_ / 16, 256, 0, stream>>>(part, scale, lora_B, bias, mid, out);
}

// Round 8
// 92.440 us; speedup vs baseline: 1.2707x; 1.1191x over previous
//
#include <hip/hip_runtime.h>
#include <stdint.h>

#define B_ 64
#define K_ 8192
#define O_ 8192
#define R_ 64
#define NSTEP 32           // K steps of 256
#define BKI 256            // ints per row per step

typedef __attribute__((ext_vector_type(8))) short s16x8;      // 8 bf16
typedef __attribute__((ext_vector_type(4))) float f32x4;
typedef __attribute__((ext_vector_type(4))) int iv4;
typedef __attribute__((ext_vector_type(4))) uint32_t uv4;

// round-to-nearest-even f32 -> bf16, packed pair
__device__ __forceinline__ uint32_t rne_pack(float a, float b) {
  uint32_t ua = __float_as_uint(a), ub = __float_as_uint(b);
  ua += 0x7fffu + ((ua >> 16) & 1u);
  ub += 0x7fffu + ((ub >> 16) & 1u);
  return (ua >> 16) | (ub & 0xffff0000u);
}

// (w - 128) in [-128,127]: EXACT in bf16, truncation suffices
__device__ __forceinline__ uint32_t wpack(int w0, int w1) {
  float f0 = (float)(w0 - 128);
  float f1 = (float)(w1 - 128);
  return (__float_as_uint(f0) >> 16) | (__float_as_uint(f1) & 0xffff0000u);
}

__device__ __forceinline__ s16x8 afrag(uv4 x) {
  union { uv4 u; s16x8 v; } r; r.u = x; return r.v;
}

// ---------------------------------------------------------------------------
// k_prep: (a) all 256 blocks: pack x (fp32 [64][8192]) into MFMA-fragment-
//         major bf16 xf: element ((C*4+m)*64 + l)*8 + j = x[m*16+(l&15)]
//         [C*32+(l>>4)*8+j].  One contiguous dwordx4 per (C,m,lane).
//         (b) blocks 0..63: partial mid = x @ lora_A^T over a 128-wide K
//         slab, accumulated via fp32 atomicAdd (mid zeroed by memset).
// ---------------------------------------------------------------------------
__global__ __launch_bounds__(256) void k_prep(
    const float* __restrict__ x, const float* __restrict__ lora_A,
    uint16_t* __restrict__ xf, float* __restrict__ mid) {
  const int t = threadIdx.x;
  const int blk = blockIdx.x;

  {  // one fragment per thread: 65536 frags = 256 blocks x 256 threads
    const int gtid = blk * 256 + t;
    const int l = gtid & 63;
    const int m = (gtid >> 6) & 3;
    const int C = gtid >> 8;
    const int row = m * 16 + (l & 15);
    const int col = C * 32 + (l >> 4) * 8;
    const float* xp = x + (size_t)row * K_ + col;
    float4 v0 = *(const float4*)xp;
    float4 v1 = *(const float4*)(xp + 4);
    uint4 p;
    p.x = rne_pack(v0.x, v0.y);
    p.y = rne_pack(v0.z, v0.w);
    p.z = rne_pack(v1.x, v1.y);
    p.w = rne_pack(v1.z, v1.w);
    *(uint4*)(xf + (size_t)gtid * 8) = p;   // coalesced
  }

  if (blk >= 64) return;

  __shared__ float xs[64][133];
  __shared__ float as_[64][133];
  const int kr0 = blk * 128;
  const int row = t >> 2, seg = t & 3;
#pragma unroll
  for (int j = 0; j < 8; ++j) {
    const int c = seg * 32 + j * 4;
    float4 vx = *(const float4*)(x + (size_t)row * K_ + kr0 + c);
    float4 va = *(const float4*)(lora_A + (size_t)row * K_ + kr0 + c);
    xs[row][c] = vx.x; xs[row][c + 1] = vx.y; xs[row][c + 2] = vx.z; xs[row][c + 3] = vx.w;
    as_[row][c] = va.x; as_[row][c + 1] = va.y; as_[row][c + 2] = va.z; as_[row][c + 3] = va.w;
  }
  __syncthreads();

  const int bg = t >> 4, rg = t & 15;
  const int b0 = bg * 4, r0 = rg * 4;
  float acc[4][4];
#pragma unroll
  for (int i = 0; i < 4; ++i)
#pragma unroll
    for (int j = 0; j < 4; ++j) acc[i][j] = 0.f;

  for (int k = 0; k < 128; ++k) {
    float xv[4], av[4];
#pragma unroll
    for (int i = 0; i < 4; ++i) xv[i] = xs[b0 + i][k];
#pragma unroll
    for (int j = 0; j < 4; ++j) av[j] = as_[r0 + j][k];
#pragma unroll
    for (int i = 0; i < 4; ++i)
#pragma unroll
      for (int j = 0; j < 4; ++j) acc[i][j] += xv[i] * av[j];
  }

#pragma unroll
  for (int i = 0; i < 4; ++i)
#pragma unroll
    for (int j = 0; j < 4; ++j)
      atomicAdd(&mid[(b0 + i) * R_ + (r0 + j)], acc[i][j]);
}

// ---------------------------------------------------------------------------
// k_main: 512 blocks x 256 threads (4 waves). Block = 16 out-rows x 64 batch
// x FULL K. Per step (BK=256 ints): each wave loads 4 W rows as 1 KB fully
// contiguous nontemporal int4 per row (copy-shaped sequential streams),
// wpack -> LDS [16][264] bf16 (2-deep reg banks, one sync per step).
// A-frags direct from L2-resident frag-major xf (1 KB contiguous per load).
// Epilogue: LoRA MFMA + scale/bias fused. No partials, no k_fin.
// ---------------------------------------------------------------------------
__global__ __launch_bounds__(256, 2) void k_main(
    const int* __restrict__ Wq, const uint16_t* __restrict__ xf,
    const float* __restrict__ scale, const float* __restrict__ lora_B,
    const float* __restrict__ bias, const float* __restrict__ mid,
    float* __restrict__ out) {
  __shared__ uint16_t wbs[2][16][264];   // stride 264 (528 B = 33x16, bank-rot 4)
  __shared__ uint16_t midb[64][72];
  __shared__ uint16_t lob[16][72];

  const int t = threadIdx.x;
  const int o0 = blockIdx.x * 16;
  const int w = t >> 6, lane = t & 63, il = lane & 15, g = lane >> 4;
  const int m0 = w * 16;

  // W row pointers: wave w owns rows 4w..4w+3; lane reads bytes lane*16
  const int* wr0 = Wq + (size_t)(o0 + 4 * w + 0) * K_ + lane * 4;
  const int* wr1 = Wq + (size_t)(o0 + 4 * w + 1) * K_ + lane * 4;
  const int* wr2 = Wq + (size_t)(o0 + 4 * w + 2) * K_ + lane * 4;
  const int* wr3 = Wq + (size_t)(o0 + 4 * w + 3) * K_ + lane * 4;

  // frag-major x base for this wave's m-slice
  const uint16_t* xbase = xf + ((size_t)w * 64 + lane) * 8;

  iv4 rA0, rA1, rA2, rA3, rB0, rB1, rB2, rB3;

#define LOADW(P, S)                                                        \
  do {                                                                     \
    r##P##0 = __builtin_nontemporal_load((const iv4*)(wr0 + (S) * BKI));   \
    r##P##1 = __builtin_nontemporal_load((const iv4*)(wr1 + (S) * BKI));   \
    r##P##2 = __builtin_nontemporal_load((const iv4*)(wr2 + (S) * BKI));   \
    r##P##3 = __builtin_nontemporal_load((const iv4*)(wr3 + (S) * BKI));   \
  } while (0)

  // start the HBM W stream immediately
  LOADW(A, 0);
  LOADW(B, 1);

  // ---- prologue: stage midb (all 256 threads) + lob (threads 0..63) ----
  {
    const int row = t >> 2;
    const int r0 = (t & 3) * 16;
    const float* mp = mid + row * R_ + r0;
    float4 a0 = *(const float4*)(mp);
    float4 a1 = *(const float4*)(mp + 4);
    float4 a2 = *(const float4*)(mp + 8);
    float4 a3 = *(const float4*)(mp + 12);
    uint4 p0, p1;
    p0.x = rne_pack(a0.x, a0.y); p0.y = rne_pack(a0.z, a0.w);
    p0.z = rne_pack(a1.x, a1.y); p0.w = rne_pack(a1.z, a1.w);
    p1.x = rne_pack(a2.x, a2.y); p1.y = rne_pack(a2.z, a2.w);
    p1.z = rne_pack(a3.x, a3.y); p1.w = rne_pack(a3.z, a3.w);
    *(uint4*)&midb[row][r0] = p0;
    *(uint4*)&midb[row][r0 + 8] = p1;
    if (t < 64) {
      const int row2 = t >> 2;
      const float* lp = lora_B + (size_t)(o0 + row2) * R_ + r0;
      float4 c0 = *(const float4*)(lp);
      float4 c1 = *(const float4*)(lp + 4);
      float4 c2 = *(const float4*)(lp + 8);
      float4 c3 = *(const float4*)(lp + 12);
      uint4 q0, q1;
      q0.x = rne_pack(c0.x, c0.y); q0.y = rne_pack(c0.z, c0.w);
      q0.z = rne_pack(c1.x, c1.y); q0.w = rne_pack(c1.z, c1.w);
      q1.x = rne_pack(c2.x, c2.y); q1.y = rne_pack(c2.z, c2.w);
      q1.z = rne_pack(c3.x, c3.y); q1.w = rne_pack(c3.z, c3.w);
      *(uint4*)&lob[row2][r0] = q0;
      *(uint4*)&lob[row2][r0 + 8] = q1;
    }
  }
  __syncthreads();

  // ---- LoRA MFMAs (proven block): acc2 = mid @ lora_B^T ----
  f32x4 acc2 = {0.f, 0.f, 0.f, 0.f};
#pragma unroll
  for (int kf = 0; kf < 2; ++kf) {
    s16x8 am = *(const s16x8*)&midb[m0 + il][kf * 32 + g * 8];
    s16x8 bl = *(const s16x8*)&lob[il][kf * 32 + g * 8];
    acc2 = __builtin_amdgcn_mfma_f32_16x16x32_bf16(am, bl, acc2, 0, 0, 0);
  }

  const float sc = scale[o0 + il];
  const float bi = bias[o0 + il];

  f32x4 acc = {0.f, 0.f, 0.f, 0.f};

  // ---- main K loop: 2-deep banks, one sync per step ----
#define STEP(P, BUF, S)                                                        \
  do {                                                                         \
    uint2 u0, u1, u2, u3;                                                      \
    u0.x = wpack(r##P##0[0], r##P##0[1]); u0.y = wpack(r##P##0[2], r##P##0[3]);\
    u1.x = wpack(r##P##1[0], r##P##1[1]); u1.y = wpack(r##P##1[2], r##P##1[3]);\
    u2.x = wpack(r##P##2[0], r##P##2[1]); u2.y = wpack(r##P##2[2], r##P##2[3]);\
    u3.x = wpack(r##P##3[0], r##P##3[1]); u3.y = wpack(r##P##3[2], r##P##3[3]);\
    *(uint2*)&wbs[BUF][4 * w + 0][lane * 4] = u0;                              \
    *(uint2*)&wbs[BUF][4 * w + 1][lane * 4] = u1;                              \
    *(uint2*)&wbs[BUF][4 * w + 2][lane * 4] = u2;                              \
    *(uint2*)&wbs[BUF][4 * w + 3][lane * 4] = u3;                              \
    __syncthreads();                                                           \
    if ((S) + 2 < NSTEP) LOADW(P, (S) + 2);                                    \
    uv4 xq0 = *(const uv4*)(xbase + ((size_t)((S) * 8 + 0)) * 2048);           \
    uv4 xq1 = *(const uv4*)(xbase + ((size_t)((S) * 8 + 1)) * 2048);           \
    uv4 xq2 = *(const uv4*)(xbase + ((size_t)((S) * 8 + 2)) * 2048);           \
    uv4 xq3 = *(const uv4*)(xbase + ((size_t)((S) * 8 + 3)) * 2048);           \
    uv4 xq4 = *(const uv4*)(xbase + ((size_t)((S) * 8 + 4)) * 2048);           \
    uv4 xq5 = *(const uv4*)(xbase + ((size_t)((S) * 8 + 5)) * 2048);           \
    uv4 xq6 = *(const uv4*)(xbase + ((size_t)((S) * 8 + 6)) * 2048);           \
    uv4 xq7 = *(const uv4*)(xbase + ((size_t)((S) * 8 + 7)) * 2048);           \
    s16x8 b0 = *(const s16x8*)&wbs[BUF][il][0 * 32 + g * 8];                   \
    acc = __builtin_amdgcn_mfma_f32_16x16x32_bf16(afrag(xq0), b0, acc, 0, 0, 0); \
    s16x8 b1 = *(const s16x8*)&wbs[BUF][il][1 * 32 + g * 8];                   \
    acc = __builtin_amdgcn_mfma_f32_16x16x32_bf16(afrag(xq1), b1, acc, 0, 0, 0); \
    s16x8 b2 = *(const s16x8*)&wbs[BUF][il][2 * 32 + g * 8];                   \
    acc = __builtin_amdgcn_mfma_f32_16x16x32_bf16(afrag(xq2), b2, acc, 0, 0, 0); \
    s16x8 b3 = *(const s16x8*)&wbs[BUF][il][3 * 32 + g * 8];                   \
    acc = __builtin_amdgcn_mfma_f32_16x16x32_bf16(afrag(xq3), b3, acc, 0, 0, 0); \
    s16x8 b4 = *(const s16x8*)&wbs[BUF][il][4 * 32 + g * 8];                   \
    acc = __builtin_amdgcn_mfma_f32_16x16x32_bf16(afrag(xq4), b4, acc, 0, 0, 0); \
    s16x8 b5 = *(const s16x8*)&wbs[BUF][il][5 * 32 + g * 8];                   \
    acc = __builtin_amdgcn_mfma_f32_16x16x32_bf16(afrag(xq5), b5, acc, 0, 0, 0); \
    s16x8 b6 = *(const s16x8*)&wbs[BUF][il][6 * 32 + g * 8];                   \
    acc = __builtin_amdgcn_mfma_f32_16x16x32_bf16(afrag(xq6), b6, acc, 0, 0, 0); \
    s16x8 b7 = *(const s16x8*)&wbs[BUF][il][7 * 32 + g * 8];                   \
    acc = __builtin_amdgcn_mfma_f32_16x16x32_bf16(afrag(xq7), b7, acc, 0, 0, 0); \
  } while (0)

  for (int s = 0; s < NSTEP; s += 2) {
    STEP(A, 0, s);
    STEP(B, 1, s + 1);
  }
#undef LOADW
#undef STEP

  // ---- epilogue: C/D layout col=il, row=(lane>>4)*4+reg ----
#pragma unroll
  for (int j = 0; j < 4; ++j) {
    const int b = m0 + g * 4 + j;
    out[(size_t)b * O_ + o0 + il] = sc * acc[j] + bi + 0.25f * acc2[j];
  }
}

// ---------------------------------------------------------------------------
extern "C" void kernel_launch(void* const* d_in, const int* in_sizes, int n_in,
                              void* d_out, int out_size, void* d_ws, size_t ws_size,
                              hipStream_t stream) {
  const float* x = (const float*)d_in[0];
  const int* Wq = (const int*)d_in[1];
  const float* scale = (const float*)d_in[2];
  const float* lora_A = (const float*)d_in[3];
  const float* lora_B = (const float*)d_in[4];
  const float* bias = (const float*)d_in[5];
  float* out = (float*)d_out;

  uint16_t* xf = (uint16_t*)d_ws;                     // 1 MiB frag-major x
  float* mid = (float*)((char*)d_ws + (2u << 20));    // 16 KiB fp32

  hipMemsetAsync(mid, 0, B_ * R_ * sizeof(float), stream);
  k_prep<<<256, 256, 0, stream>>>(x, lora_A, xf, mid);
  k_main<<<O_ / 16, 256, 0, stream>>>(Wq, xf, scale, lora_B, bias, mid, out);
}